// Round 7
// baseline (389.815 us; speedup 1.0000x reference)
//
#include <hip/hip_runtime.h>
#include <math.h>

// ---------------------------------------------------------------------------
// BasedBlock: B=4 L=2048 d=1024 h=16 f=16 hd=64 w=64, D=1+f+f*f=273
// Round 12: REVERT the phaseA2/phaseC4 XCD remap (round-11 regression:
// phaseC4 <40 -> 55.5us). Natural order orig=bh*16+ck already groups
// same-ck blocks (which share qkv lines) onto one XCD: ck mod 8 == orig mod 8.
// Keep: GEMM XCD swizzle, prep_all fusion, bf16 intermediates.
// ---------------------------------------------------------------------------

#define LL 2048
#define DD 1024
#define DFEAT 273
#define NC 16
#define CHUNK 128
#define QKVN 1536

typedef __attribute__((ext_vector_type(8))) short short8;
typedef __attribute__((ext_vector_type(4))) float f32x4;

#define SQ 0.42044820762685725f   // sqrt(1/(sqrt(2)*sqrt(16)))
#define LF 1.18920711500272107f   // 0.5 / SQ

__device__ __forceinline__ float4 f4(float a, float b, float c, float d) {
  float4 r; r.x = a; r.y = b; r.z = c; r.w = d; return r;
}

__device__ __forceinline__ unsigned short f2bf(float f) {
  union { float f; unsigned u; } v; v.f = f;
  unsigned r = v.u + 0x7fffu + ((v.u >> 16) & 1u);
  return (unsigned short)(r >> 16);
}

__device__ __forceinline__ float bf2f(unsigned short u) {
  union { unsigned u; float f; } v; v.u = ((unsigned)u) << 16; return v.f;
}

// ------------------------------ prep_all -----------------------------------
// Blocks [0,8192): x fp32 -> bf16. [8192,9344): the 6 weight transposes
// (+ bias concat). [9344,9376): klast/vlast = bias init.
__global__ __launch_bounds__(256) void prep_all(
    const float* __restrict__ x, unsigned short* __restrict__ x_bf,
    const float* __restrict__ Wql, const float* __restrict__ Wkl,
    const float* __restrict__ Wvl, const float* __restrict__ Wo1,
    const float* __restrict__ Wq2, const float* __restrict__ Wo2,
    const float* __restrict__ bql, const float* __restrict__ bkl,
    const float* __restrict__ bvl,
    unsigned short* __restrict__ Wcomb, unsigned short* __restrict__ WtO1,
    unsigned short* __restrict__ WtQ2, unsigned short* __restrict__ WtO2,
    float* __restrict__ bqkv,
    const float* __restrict__ bk, const float* __restrict__ bv,
    float* __restrict__ klast, float* __restrict__ vlast) {
  __shared__ float t[64][65];
  const int blk = blockIdx.x, tid = threadIdx.x;
  if (blk < 8192) {
    int i = blk * 256 + tid;
    float4 v = ((const float4*)x)[i];
    ushort4 r;
    r.x = f2bf(v.x); r.y = f2bf(v.y); r.z = f2bf(v.z); r.w = f2bf(v.w);
    ((ushort4*)x_bf)[i] = r;
    return;
  }
  if (blk >= 9344) {
    int gid = (blk - 9344) * 256 + tid;   // 0..8191
    int which = gid >> 12;
    int b = (gid >> 10) & 3;
    int n = gid & 1023;
    (which ? vlast : klast)[b * 1024 + n] = which ? bv[n] : bk[n];
    return;
  }
  const int b2 = blk - 8192;   // 0..1151
  if (b2 < 6) {
    int i = b2 * 256 + tid;   // 0..1535
    float v = (i < 256) ? bql[i] : (i < 512) ? bkl[i - 256] : bvl[i - 512];
    bqkv[i] = v;
  }
  const float* W; unsigned short* Wt; int N, t0;
  if (b2 < 64)       { W = Wql; Wt = Wcomb;               N = 256;  t0 = b2; }
  else if (b2 < 128) { W = Wkl; Wt = Wcomb + 256 * 1024;  N = 256;  t0 = b2 - 64; }
  else if (b2 < 384) { W = Wvl; Wt = Wcomb + 512 * 1024;  N = 1024; t0 = b2 - 128; }
  else if (b2 < 640) { W = Wo1; Wt = WtO1;                N = 1024; t0 = b2 - 384; }
  else if (b2 < 896) { W = Wq2; Wt = WtQ2;                N = 1024; t0 = b2 - 640; }
  else               { W = Wo2; Wt = WtO2;                N = 1024; t0 = b2 - 896; }
  const int nt = N >> 6;
  const int k0 = (t0 / nt) * 64, n0 = (t0 % nt) * 64;
#pragma unroll
  for (int p = 0; p < 16; p++) {
    int idx = p * 256 + tid;
    int r = idx >> 6, c = idx & 63;
    t[r][c] = W[(size_t)(k0 + r) * N + n0 + c];
  }
  __syncthreads();
#pragma unroll
  for (int p = 0; p < 16; p++) {
    int idx = p * 256 + tid;
    int rn = idx >> 6, ck = idx & 63;
    Wt[(size_t)(n0 + rn) * 1024 + k0 + ck] = f2bf(t[ck][rn]);
  }
}

// --------------------------- MFMA GEMM -------------------------------------
// 1-D grid; XCD-aware bijective swizzle (nwg % 8 == 0 for all call sites),
// row-major decode so each XCD owns a contiguous band of row-tiles.
__global__ __launch_bounds__(256) void gemm_mfma(
    const unsigned short* __restrict__ A, const unsigned short* __restrict__ Bt,
    const float* __restrict__ bias, float* __restrict__ C,
    unsigned short* __restrict__ Cb, int M, int N, int K) {
  __shared__ unsigned short As[128 * 64];
  __shared__ unsigned short Bs[128 * 64];
  const int tid = threadIdx.x;
  const int lane = tid & 63, w = tid >> 6;
  const int Ny = N >> 7;
  const int cpx = gridDim.x >> 3;
  const int orig = blockIdx.x;
  const int wg = (orig & 7) * cpx + (orig >> 3);
  const int bxi = wg / Ny, byi = wg - bxi * Ny;
  const int row0 = bxi * 128, col0 = byi * 128;
  const int wm0 = (w & 1) * 64, wn0 = (w >> 1) * 64;
  const int lr = lane >> 3;
  const int gc = (lane & 7) ^ lr;
  const unsigned short* aP = A + (size_t)(row0 + w * 32 + lr) * K + gc * 8;
  const unsigned short* bP = Bt + (size_t)(col0 + w * 32 + lr) * K + gc * 8;
  unsigned short* asW = As + w * 2048;
  unsigned short* bsW = Bs + w * 2048;
  const int m15 = lane & 15, quad = lane >> 4;
  f32x4 acc[4][4] = {};
  for (int k0 = 0; k0 < K; k0 += 64) {
#pragma unroll
    for (int i = 0; i < 4; i++) {
      __builtin_amdgcn_global_load_lds(
          (const __attribute__((address_space(1))) unsigned int*)(const void*)(aP + (size_t)(i * 8) * K + k0),
          (__attribute__((address_space(3))) unsigned int*)(void*)(asW + i * 512), 16, 0, 0);
      __builtin_amdgcn_global_load_lds(
          (const __attribute__((address_space(1))) unsigned int*)(const void*)(bP + (size_t)(i * 8) * K + k0),
          (__attribute__((address_space(3))) unsigned int*)(void*)(bsW + i * 512), 16, 0, 0);
    }
    __syncthreads();
#pragma unroll
    for (int ks = 0; ks < 2; ks++) {
      short8 aF[4], bF[4];
#pragma unroll
      for (int mi = 0; mi < 4; mi++) {
        int r = wm0 + mi * 16 + m15;
        int g = (ks * 4 + quad) ^ (r & 7);
        aF[mi] = *(const short8*)(As + r * 64 + g * 8);
      }
#pragma unroll
      for (int ni = 0; ni < 4; ni++) {
        int r = wn0 + ni * 16 + m15;
        int g = (ks * 4 + quad) ^ (r & 7);
        bF[ni] = *(const short8*)(Bs + r * 64 + g * 8);
      }
#pragma unroll
      for (int mi = 0; mi < 4; mi++)
#pragma unroll
        for (int ni = 0; ni < 4; ni++)
          acc[mi][ni] = __builtin_amdgcn_mfma_f32_16x16x32_bf16(
              aF[mi], bF[ni], acc[mi][ni], 0, 0, 0);
    }
    __syncthreads();
  }
#pragma unroll
  for (int mi = 0; mi < 4; mi++)
#pragma unroll
    for (int ni = 0; ni < 4; ni++) {
      int col = col0 + wn0 + ni * 16 + m15;
      float bb = bias[col];
#pragma unroll
      for (int r = 0; r < 4; r++) {
        int row = row0 + wm0 + mi * 16 + quad * 4 + r;
        float val = acc[mi][ni][r] + bb;
        if (Cb) Cb[(size_t)row * N + col] = f2bf(val);
        else C[(size_t)row * N + col] = val;
      }
    }
}

// ------------------------------ transV -------------------------------------
// qkv[t][512 + h*64+c] -> vT[bh][c][t]
__global__ __launch_bounds__(256) void transV(
    const unsigned short* __restrict__ qkv, unsigned short* __restrict__ vT) {
  __shared__ unsigned short Tv[64][72];
  const int blk = blockIdx.x;
  const int bh = blk >> 5, tt = blk & 31;
  const int b = bh >> 4, hh = bh & 15;
  const int t0 = tt * 64;
  const int tid = threadIdx.x;
  {
    int t = tid >> 2, cs = tid & 3;
    const unsigned short* p = qkv + ((size_t)(b * LL + t0 + t)) * QKVN + 512 + hh * 64 + cs * 16;
    *(short8*)&Tv[t][cs * 16] = *(const short8*)p;
    *(short8*)&Tv[t][cs * 16 + 8] = *(const short8*)(p + 8);
  }
  __syncthreads();
  {
    int c = tid & 63, ts = tid >> 6;
    unsigned short vals[16];
#pragma unroll
    for (int j = 0; j < 16; j++) vals[j] = Tv[ts * 16 + j][c];
    unsigned short* op = vT + ((size_t)bh * 64 + c) * LL + t0 + ts * 16;
    *(short8*)op = *(short8*)&vals[0];
    *(short8*)(op + 8) = *(short8*)&vals[8];
  }
}

// ------------------------------ phase A ------------------------------------
// KVc_t[bh][ck][c][f] = sum_t Kf[t][f] V[t][c] (bf16); kstc[bh][ck][f].
// Natural block order (ck mod 8 == blockIdx mod 8 -> same-ck blocks share XCD).
__global__ __launch_bounds__(256) void phaseA2(
    const unsigned short* __restrict__ qkv, const unsigned short* __restrict__ vT,
    unsigned short* __restrict__ KVc_t, unsigned short* __restrict__ kstc) {
  __shared__ unsigned short kT[16][136];   // kT[i][t] = bf16(k[t][i]*SQ)
  const int tid = threadIdx.x, lane = tid & 63, w = tid >> 6;
  const int m15 = lane & 15, quad = lane >> 4;
  const int bh = blockIdx.x >> 4, ck = blockIdx.x & 15;
  const int b = bh >> 4, hh = bh & 15;
  const int t0 = ck * CHUNK;
  {
    int r = tid >> 1, half = tid & 1;
    short8 kv = *(const short8*)(qkv + ((size_t)(b * LL + t0 + r)) * QKVN + 256 + hh * 16 + half * 8);
#pragma unroll
    for (int j = 0; j < 8; j++)
      kT[half * 8 + j][r] = f2bf(bf2f(((unsigned short*)&kv)[j]) * SQ);
  }
  __syncthreads();
  short8 ones8 = {16256, 16256, 16256, 16256, 16256, 16256, 16256, 16256};
  short8 zer8 = {0, 0, 0, 0, 0, 0, 0, 0};
  f32x4 acc[5][5] = {};
  const unsigned short* vbase = vT + (size_t)bh * 64 * LL + t0;
#pragma unroll
  for (int ks = 0; ks < 4; ++ks) {
    const int tt = ks * 32 + quad * 8;
    short8 aF[5], bF[5];
#pragma unroll
    for (int mi = 0; mi < 5; mi++) {
      int r = (w * 5 + mi) * 16 + m15;
      short8 av;
      unsigned short* pv = (unsigned short*)&av;
      if (r == 0) {
        av = ones8;
      } else if (r < 17) {
        short8 k1 = *(const short8*)&kT[r - 1][tt];
#pragma unroll
        for (int j = 0; j < 8; j++) pv[j] = f2bf(bf2f(((unsigned short*)&k1)[j]) * LF);
      } else if (r < DFEAT) {
        int ij = r - 17;
        short8 k1 = *(const short8*)&kT[ij >> 4][tt];
        short8 k2 = *(const short8*)&kT[ij & 15][tt];
#pragma unroll
        for (int j = 0; j < 8; j++)
          pv[j] = f2bf(bf2f(((unsigned short*)&k1)[j]) * bf2f(((unsigned short*)&k2)[j]));
      } else {
        av = zer8;
      }
      aF[mi] = av;
    }
#pragma unroll
    for (int ni = 0; ni < 4; ni++)
      bF[ni] = *(const short8*)(vbase + ((size_t)(ni * 16 + m15)) * LL + tt);
    bF[4] = (m15 == 0) ? ones8 : zer8;
#pragma unroll
    for (int mi = 0; mi < 5; mi++)
#pragma unroll
      for (int ni = 0; ni < 5; ni++)
        acc[mi][ni] = __builtin_amdgcn_mfma_f32_16x16x32_bf16(
            aF[mi], bF[ni], acc[mi][ni], 0, 0, 0);
  }
  const size_t cb = ((size_t)bh * NC + ck) * (64 * 288);
  const size_t kb = ((size_t)bh * NC + ck) * 288;
#pragma unroll
  for (int mi = 0; mi < 5; mi++) {
    int fb = (w * 5 + mi) * 16 + quad * 4;
    if (fb < 288) {
#pragma unroll
      for (int ni = 0; ni < 4; ni++) {
        int c = ni * 16 + m15;
        ushort4 sv;
        sv.x = f2bf(acc[mi][ni][0]); sv.y = f2bf(acc[mi][ni][1]);
        sv.z = f2bf(acc[mi][ni][2]); sv.w = f2bf(acc[mi][ni][3]);
        *(ushort4*)(KVc_t + cb + (size_t)c * 288 + fb) = sv;
      }
      if (m15 == 0) {
        ushort4 sv;
        sv.x = f2bf(acc[mi][4][0]); sv.y = f2bf(acc[mi][4][1]);
        sv.z = f2bf(acc[mi][4][2]); sv.w = f2bf(acc[mi][4][3]);
        *(ushort4*)(kstc + kb + fb) = sv;
      }
    }
  }
}

// ------------------------------ phase B ------------------------------------
__global__ __launch_bounds__(256) void phaseB3(
    const unsigned short* __restrict__ KVc_t, const unsigned short* __restrict__ kstc,
    const float* __restrict__ kv0, const float* __restrict__ kst0,
    unsigned short* __restrict__ KVp_t, unsigned short* __restrict__ kstp,
    float* __restrict__ kv_out, float* __restrict__ kst_out) {
  const int tid = threadIdx.x;
  if (blockIdx.x < 576) {
    int gid = blockIdx.x * 256 + tid;
    int bh = gid / 2304, rem = gid - bh * 2304;
    int c = rem / 36, fg = rem - c * 36;
    int f0 = fg * 8;
    float acc[8];
#pragma unroll
    for (int j = 0; j < 8; j++) {
      int f = f0 + j;
      acc[j] = (f < DFEAT) ? kv0[((size_t)bh * DFEAT + f) * 64 + c] : 0.0f;
    }
    size_t base = ((size_t)bh * NC) * (64 * 288) + (size_t)c * 288 + f0;
    for (int ck = 0; ck < NC; ck++) {
      size_t idx = base + (size_t)ck * (64 * 288);
      short8 t = *(const short8*)(KVc_t + idx);
      unsigned short ov[8];
#pragma unroll
      for (int j = 0; j < 8; j++) {
        ov[j] = f2bf(acc[j]);
        acc[j] += bf2f(((unsigned short*)&t)[j]);
      }
      *(short8*)(KVp_t + idx) = *(short8*)ov;
    }
#pragma unroll
    for (int j = 0; j < 8; j++) {
      int f = f0 + j;
      if (f < DFEAT) kv_out[((size_t)bh * DFEAT + f) * 64 + c] = acc[j];
    }
  } else {
    int idx0 = (blockIdx.x - 576) * 256 + tid;   // 0..2303
    int bh = idx0 / 36, fg = idx0 - bh * 36;
    int f0 = fg * 8;
    float acc[8];
#pragma unroll
    for (int j = 0; j < 8; j++) {
      int f = f0 + j;
      acc[j] = (f < DFEAT) ? kst0[bh * DFEAT + f] : 0.0f;
    }
    for (int ck = 0; ck < NC; ck++) {
      size_t idx = ((size_t)bh * NC + ck) * 288 + f0;
      short8 t = *(const short8*)(kstc + idx);
      unsigned short ov[8];
#pragma unroll
      for (int j = 0; j < 8; j++) {
        ov[j] = f2bf(acc[j]);
        acc[j] += bf2f(((unsigned short*)&t)[j]);
      }
      *(short8*)(kstp + idx) = *(short8*)ov;
    }
#pragma unroll
    for (int j = 0; j < 8; j++) {
      int f = f0 + j;
      if (f < DFEAT) kst_out[bh * DFEAT + f] = acc[j];
    }
  }
}

// ------------------------------ phase C ------------------------------------
// 256-thread blocks, grid 1024 = (bh, ck) natural order; wave w = quarter qw.
__global__ __launch_bounds__(256) void phaseC4(
    const unsigned short* __restrict__ qkv,
    const unsigned short* __restrict__ vT, const unsigned short* __restrict__ KVp_t,
    const unsigned short* __restrict__ kstp, unsigned short* __restrict__ outs) {
  __shared__ float qs[4][32][36];              // per-wave: [0..15]=q*SQ, [16..31]=rot dup
  __shared__ unsigned short S_l[4][32 * 128];  // per-wave swizzled intra scores
  const int tid = threadIdx.x, lane = tid & 63, w = tid >> 6;
  const int m15 = lane & 15, quad = lane >> 4;
  const int bh = blockIdx.x >> 4, ck = blockIdx.x & 15;
  const int qw = w;
  const int b = bh >> 4, hh = bh & 15;
  const int t0 = ck * CHUNK;
  const int tr0 = qw * 32;
  float (*qsw)[36] = qs[w];
  unsigned short* Sw = S_l[w];
  const unsigned short* qbase = qkv + ((size_t)(b * LL + t0 + tr0)) * QKVN + hh * 16;
  const unsigned short* kbase = qkv + ((size_t)(b * LL + t0)) * QKVN + 256 + hh * 16;
  // ---- fill qs (wave-private rows, no barrier) ----
  {
    int r = lane >> 1, h8 = lane & 1;
    short8 qv = *(const short8*)(qbase + (size_t)r * QKVN + h8 * 8);
    float qf[8];
#pragma unroll
    for (int j = 0; j < 8; j++) qf[j] = bf2f(((unsigned short*)&qv)[j]) * SQ;
    *(float4*)&qsw[r][h8 * 8] = f4(qf[0], qf[1], qf[2], qf[3]);
    *(float4*)&qsw[r][h8 * 8 + 4] = f4(qf[4], qf[5], qf[6], qf[7]);
#pragma unroll
    for (int j = 0; j < 8; j++)
      qsw[r][16 + ((h8 * 8 + j + 9) & 15)] = qf[j];   // rot[m] = q[(m+7)&15]
  }
  short8 ones8 = {16256, 16256, 16256, 16256, 16256, 16256, 16256, 16256};
  short8 zer8 = {0, 0, 0, 0, 0, 0, 0, 0};
  f32x4 acc[2][5] = {};
  const unsigned short* KVb = KVp_t + ((size_t)(bh * NC + ck)) * (64 * 288);
  const unsigned short* kstb = kstp + ((size_t)(bh * NC + ck)) * 288;
  // ---- pass 1: inter (Qf @ KV'), K = 288 ----
#pragma unroll
  for (int ks = 0; ks < 9; ++ks) {
    const int fs = ks * 32 + quad * 8;
    short8 aF[2], bF[5];
#pragma unroll
    for (int ni = 0; ni < 4; ni++)
      bF[ni] = *(const short8*)(KVb + ((size_t)(ni * 16 + m15)) * 288 + fs);
    bF[4] = (m15 == 0) ? *(const short8*)(kstb + fs) : zer8;
#pragma unroll
    for (int mi = 0; mi < 2; mi++) {
      const float* qr = &qsw[mi * 16 + m15][0];
      unsigned short pv[8];
      if (ks == 0) {
        float qr0 = qr[0];
#pragma unroll
        for (int j = 0; j < 8; j++) {
          int f = (quad << 3) + j;
          int fl = f - 1; fl = fl < 0 ? 0 : fl;
          int fm = f - 17; fm = fm < 0 ? 0 : fm;     // < 16 here
          float lin = qr[fl] * LF;
          float prod = qr0 * qr[fm];
          float val = (f == 0) ? 1.0f : ((f < 17) ? lin : prod);
          pv[j] = f2bf(val);
        }
      } else {
        int base = fs - 17;                 // >= 15
        int i0 = base >> 4;
        float qi0 = qr[i0];
        float qi1 = qr[i0 + 1];
        const float* qv = qr + 16 + (base & 8);   // aligned 32B window (rot dup)
        float qj[8];
        *(float4*)&qj[0] = *(const float4*)qv;
        *(float4*)&qj[4] = *(const float4*)(qv + 4);
        float qiB = (quad & 1) ? qi0 : qi1;
#pragma unroll
        for (int j = 0; j < 8; j++) {
          float qi = (j == 0) ? qi0 : qiB;
          float val = qi * qj[j];
          if (ks == 8) val = ((quad << 3) + j < 17) ? val : 0.0f;  // f >= 273 -> 0
          pv[j] = f2bf(val);
        }
      }
      aF[mi] = *(short8*)pv;
    }
#pragma unroll
    for (int mi = 0; mi < 2; mi++)
#pragma unroll
      for (int ni = 0; ni < 5; ni++)
        acc[mi][ni] = __builtin_amdgcn_mfma_f32_16x16x32_bf16(
            aF[mi], bF[ni], acc[mi][ni], 0, 0, 0);
  }
  // ---- intra: u = q@k^T (K=16 pad 32) -> poly/mask -> S_l (wave-private) ----
  const int nsn = 2 * qw + 2;               // s covers [0, (qw+1)*32)
  {
    short8 aU[2], bU[8];
    aU[0] = (quad < 2) ? *(const short8*)(qbase + (size_t)m15 * QKVN + quad * 8) : zer8;
    aU[1] = (quad < 2) ? *(const short8*)(qbase + (size_t)(16 + m15) * QKVN + quad * 8) : zer8;
#pragma unroll
    for (int sn = 0; sn < 8; sn++) {
      if (sn < nsn) {
        int s = sn * 16 + m15;
        bU[sn] = (quad < 2) ? *(const short8*)(kbase + (size_t)s * QKVN + quad * 8) : zer8;
      }
    }
#pragma unroll
    for (int mi = 0; mi < 2; mi++) {
#pragma unroll
      for (int sn = 0; sn < 8; sn++) {
        if (sn < nsn) {
          f32x4 zz = {0.f, 0.f, 0.f, 0.f};
          f32x4 u = __builtin_amdgcn_mfma_f32_16x16x32_bf16(aU[mi], bU[sn], zz, 0, 0, 0);
          int s = sn * 16 + m15;
          int gRow = s >> 3;
#pragma unroll
          for (int rr = 0; rr < 4; rr++) {
            int tl = mi * 16 + quad * 4 + rr;        // local row 0..31
            int tc = tr0 + tl;                       // chunk-local row for mask
            float uu = u[rr];
            float sv = (s <= tc) ? fmaf(uu, fmaf(uu, 0.03125f, 0.25f), 1.0f) : 0.0f;
            int p = gRow ^ (tl & 7);
            Sw[tl * 128 + p * 8 + (s & 7)] = f2bf(sv);
          }
        }
      }
    }
  }
  // ---- pass 2: S @ V' — no barrier (same-wave LDS RAW) ----
  const unsigned short* vbase = vT + (size_t)bh * 64 * LL + t0;
#pragma unroll
  for (int ks = 0; ks < 4; ++ks) {
    if (ks <= qw) {
      const int tt = ks * 32 + quad * 8;
      short8 aF[2], bF[5];
#pragma unroll
      for (int mi = 0; mi < 2; mi++) {
        int tl = mi * 16 + m15;
        int p = (ks * 4 + quad) ^ (tl & 7);
        aF[mi] = *(const short8*)&Sw[tl * 128 + p * 8];
      }
#pragma unroll
      for (int ni = 0; ni < 4; ni++)
        bF[ni] = *(const short8*)(vbase + ((size_t)(ni * 16 + m15)) * LL + tt);
      bF[4] = (m15 == 0) ? ones8 : zer8;
#pragma unroll
      for (int mi = 0; mi < 2; mi++)
#pragma unroll
        for (int ni = 0; ni < 5; ni++)
          acc[mi][ni] = __builtin_amdgcn_mfma_f32_16x16x32_bf16(
              aF[mi], bF[ni], acc[mi][ni], 0, 0, 0);
    }
  }
  // ---- epilogue ----
#pragma unroll
  for (int mi = 0; mi < 2; mi++) {
#pragma unroll
    for (int rr = 0; rr < 4; rr++) {
      float den = __shfl(acc[mi][4][rr], (lane & 48));
      float inv = 1.0f / (den + 1e-6f);
      int tl = mi * 16 + quad * 4 + rr;
      unsigned short* op = outs + ((size_t)(b * LL + t0 + tr0 + tl)) * DD + hh * 64;
#pragma unroll
      for (int ni = 0; ni < 4; ni++)
        op[ni * 16 + m15] = f2bf(acc[mi][ni][rr] * inv);
    }
  }
}

// --------------------------- last-row k2/v2 --------------------------------
// grid 512 = which(2) x nstrip(16) x kslice(16); bf16 x1 input.
__global__ __launch_bounds__(256) void lastrow_qkv2(
    const unsigned short* __restrict__ x1b,
    const float* __restrict__ Wk, const float* __restrict__ Wv,
    float* __restrict__ klast, float* __restrict__ vlast) {
  __shared__ float xs[4][64];
  __shared__ float red[4][4][64];
  const int blk = blockIdx.x;
  const int which = blk >> 8;
  const int nstrip = (blk >> 4) & 15;
  const int kslice = blk & 15;
  const int n0 = nstrip * 64, k0 = kslice * 64;
  const int tid = threadIdx.x;
  const int nn = tid & 63, p = tid >> 6;
  {
    int b = tid >> 6, k = tid & 63;
    xs[b][k] = bf2f(x1b[((size_t)(b * LL + LL - 1)) * DD + k0 + k]);
  }
  __syncthreads();
  const float* W = which ? Wv : Wk;
  float acc[4] = {};
#pragma unroll
  for (int i = 0; i < 16; i++) {
    int kk = p * 16 + i;
    float wv = W[(size_t)(k0 + kk) * 1024 + n0 + nn];
#pragma unroll
    for (int b = 0; b < 4; b++) acc[b] = fmaf(xs[b][kk], wv, acc[b]);
  }
#pragma unroll
  for (int b = 0; b < 4; b++) red[p][b][nn] = acc[b];
  __syncthreads();
  if (p == 0) {
    float* outp = which ? vlast : klast;
#pragma unroll
    for (int b = 0; b < 4; b++) {
      float s = red[0][b][nn] + red[1][b][nn] + red[2][b][nn] + red[3][b][nn];
      atomicAdd(outp + b * 1024 + n0 + nn, s);
    }
  }
}

// --------------------------- window prep -----------------------------------
__global__ __launch_bounds__(256) void prep_window(
    const float* __restrict__ kbuf, const float* __restrict__ vbufw,
    const float* __restrict__ klast, const float* __restrict__ vlast,
    unsigned short* __restrict__ ukb, unsigned short* __restrict__ uvT) {
  __shared__ float Tv[64][68];
  const int bh = blockIdx.x;
  const int b = bh >> 4, hh = bh & 15;
  const int tid = threadIdx.x;
  const int wi = tid >> 2, d0 = (tid & 3) * 16;
  {
    const float* kp = (wi < 63) ? (kbuf + ((size_t)hh * 64 + wi + 1) * 64 + d0)
                                : (klast + (size_t)b * 1024 + hh * 64 + d0);
    unsigned short* op = ukb + ((size_t)bh * 64 + wi) * 64 + d0;
#pragma unroll
    for (int j4 = 0; j4 < 4; j4++) {
      float4 v = *(const float4*)(kp + j4 * 4);
      ushort4 r;
      r.x = f2bf(v.x); r.y = f2bf(v.y); r.z = f2bf(v.z); r.w = f2bf(v.w);
      *(ushort4*)(op + j4 * 4) = r;
    }
  }
  {
    const float* vp = (wi < 63) ? (vbufw + ((size_t)hh * 64 + wi + 1) * 64 + d0)
                                : (vlast + (size_t)b * 1024 + hh * 64 + d0);
#pragma unroll
    for (int j4 = 0; j4 < 4; j4++)
      *(float4*)&Tv[wi][d0 + j4 * 4] = *(const float4*)(vp + j4 * 4);
  }
  __syncthreads();
  {
    int c = tid & 63, w0 = (tid >> 6) * 16;
    unsigned short* op = uvT + ((size_t)bh * 64 + c) * 64 + w0;
    unsigned short vals[16];
#pragma unroll
    for (int j = 0; j < 16; j++) vals[j] = f2bf(Tv[w0 + j][c]);
    *(short8*)op = *(short8*)&vals[0];
    *(short8*)(op + 8) = *(short8*)&vals[8];
  }
}

// --------------------------- window attention ------------------------------
__global__ __launch_bounds__(256) void window_attn2(
    const unsigned short* __restrict__ q2b, const unsigned short* __restrict__ ukb,
    const unsigned short* __restrict__ uvT, unsigned short* __restrict__ win) {
  __shared__ unsigned short S_l[128 * 64];   // 16 KB, swizzled softmax weights
  const int tid = threadIdx.x, lane = tid & 63, w = tid >> 6;
  const int m15 = lane & 15, quad = lane >> 4;
  const int bh = blockIdx.x >> 4, tile = blockIdx.x & 15;
  const int b = bh >> 4, hh = bh & 15;
  const int t0 = tile * 128 + w * 32;
  const unsigned short* ukbase = ukb + (size_t)bh * 64 * 64;
  const unsigned short* uvbase = uvT + (size_t)bh * 64 * 64;
  f32x4 accS[2][4] = {};
#pragma unroll
  for (int ks = 0; ks < 2; ks++) {
    short8 aF[2], bF[4];
#pragma unroll
    for (int mi = 0; mi < 2; mi++)
      aF[mi] = *(const short8*)(q2b + ((size_t)(b * LL + t0 + mi * 16 + m15)) * DD +
                                hh * 64 + ks * 32 + quad * 8);
#pragma unroll
    for (int ni = 0; ni < 4; ni++)
      bF[ni] = *(const short8*)(ukbase + ((size_t)(ni * 16 + m15)) * 64 + ks * 32 + quad * 8);
#pragma unroll
    for (int mi = 0; mi < 2; mi++)
#pragma unroll
      for (int ni = 0; ni < 4; ni++)
        accS[mi][ni] = __builtin_amdgcn_mfma_f32_16x16x32_bf16(
            aF[mi], bF[ni], accS[mi][ni], 0, 0, 0);
  }
#pragma unroll
  for (int mi = 0; mi < 2; mi++) {
#pragma unroll
    for (int rr = 0; rr < 4; rr++) {
      float s0 = accS[mi][0][rr] * 0.125f;
      float s1 = accS[mi][1][rr] * 0.125f;
      float s2 = accS[mi][2][rr] * 0.125f;
      float s3 = accS[mi][3][rr] * 0.125f;
      float m = fmaxf(fmaxf(s0, s1), fmaxf(s2, s3));
      m = fmaxf(m, __shfl_xor(m, 1));
      m = fmaxf(m, __shfl_xor(m, 2));
      m = fmaxf(m, __shfl_xor(m, 4));
      m = fmaxf(m, __shfl_xor(m, 8));
      float p0 = __expf(s0 - m), p1 = __expf(s1 - m);
      float p2 = __expf(s2 - m), p3 = __expf(s3 - m);
      float l = p0 + p1 + p2 + p3;
      l += __shfl_xor(l, 1);
      l += __shfl_xor(l, 2);
      l += __shfl_xor(l, 4);
      l += __shfl_xor(l, 8);
      float inv = 1.0f / l;
      int tl = w * 32 + mi * 16 + quad * 4 + rr;
      int t7 = tl & 7;
      float pr[4] = {p0 * inv, p1 * inv, p2 * inv, p3 * inv};
#pragma unroll
      for (int ni = 0; ni < 4; ni++) {
        int s = ni * 16 + m15;
        S_l[tl * 64 + ((s >> 3) ^ t7) * 8 + (s & 7)] = f2bf(pr[ni]);
      }
    }
  }
  f32x4 accO[2][4] = {};
#pragma unroll
  for (int ks = 0; ks < 2; ks++) {
    short8 aF[2], bF[4];
#pragma unroll
    for (int mi = 0; mi < 2; mi++) {
      int tl = w * 32 + mi * 16 + m15;
      int g = (ks * 4 + quad) ^ (tl & 7);
      aF[mi] = *(const short8*)&S_l[tl * 64 + g * 8];
    }
#pragma unroll
    for (int ni = 0; ni < 4; ni++)
      bF[ni] = *(const short8*)(uvbase + ((size_t)(ni * 16 + m15)) * 64 + ks * 32 + quad * 8);
#pragma unroll
    for (int mi = 0; mi < 2; mi++)
#pragma unroll
      for (int ni = 0; ni < 4; ni++)
        accO[mi][ni] = __builtin_amdgcn_mfma_f32_16x16x32_bf16(
            aF[mi], bF[ni], accO[mi][ni], 0, 0, 0);
  }
#pragma unroll
  for (int mi = 0; mi < 2; mi++) {
#pragma unroll
    for (int rr = 0; rr < 4; rr++) {
      int row = t0 + mi * 16 + quad * 4 + rr;
      unsigned short* op = win + ((size_t)(b * LL + row)) * DD + hh * 64;
#pragma unroll
      for (int ni = 0; ni < 4; ni++)
        op[ni * 16 + m15] = f2bf(accO[mi][ni][rr]);
    }
  }
}

// ------------------------------ LayerNorm ----------------------------------
// A = Af (fp32) or Ab (bf16); Bm = bf16; outputs optional.
__global__ __launch_bounds__(256) void ln_add2(
    const float* __restrict__ Af, const unsigned short* __restrict__ Ab,
    const unsigned short* __restrict__ Bmb,
    const float* __restrict__ gamma, const float* __restrict__ beta,
    float* __restrict__ out, unsigned short* __restrict__ outb) {
  const int row = blockIdx.x, tid = threadIdx.x;
  float a0, a1, a2, a3;
  if (Af) {
    float4 va = ((const float4*)(Af + (size_t)row * DD))[tid];
    a0 = va.x; a1 = va.y; a2 = va.z; a3 = va.w;
  } else {
    ushort4 ua = ((const ushort4*)(Ab + (size_t)row * DD))[tid];
    a0 = bf2f(ua.x); a1 = bf2f(ua.y); a2 = bf2f(ua.z); a3 = bf2f(ua.w);
  }
  ushort4 ub = ((const ushort4*)(Bmb + (size_t)row * DD))[tid];
  float4 s4 = f4(a0 + bf2f(ub.x), a1 + bf2f(ub.y), a2 + bf2f(ub.z), a3 + bf2f(ub.w));
  float s = s4.x + s4.y + s4.z + s4.w;
  float ss = s4.x * s4.x + s4.y * s4.y + s4.z * s4.z + s4.w * s4.w;
  for (int o = 32; o; o >>= 1) { s += __shfl_xor(s, o); ss += __shfl_xor(ss, o); }
  __shared__ float red[8];
  int wid = tid >> 6;
  if ((tid & 63) == 0) { red[wid * 2] = s; red[wid * 2 + 1] = ss; }
  __syncthreads();
  float tot = red[0] + red[2] + red[4] + red[6];
  float tots = red[1] + red[3] + red[5] + red[7];
  float mu = tot * (1.0f / 1024.0f);
  float var = tots * (1.0f / 1024.0f) - mu * mu;
  float rstd = rsqrtf(var + 1e-5f);
  float4 g = ((const float4*)gamma)[tid];
  float4 be = ((const float4*)beta)[tid];
  float4 o = f4((s4.x - mu) * rstd * g.x + be.x, (s4.y - mu) * rstd * g.y + be.y,
                (s4.z - mu) * rstd * g.z + be.z, (s4.w - mu) * rstd * g.w + be.w);
  if (out) ((float4*)(out + (size_t)row * DD))[tid] = o;
  if (outb) {
    ushort4 r;
    r.x = f2bf(o.x); r.y = f2bf(o.y); r.z = f2bf(o.z); r.w = f2bf(o.w);
    ((ushort4*)(outb + (size_t)row * DD))[tid] = r;
  }
}

// ------------------------------ launch -------------------------------------
extern "C" void kernel_launch(void* const* d_in, const int* in_sizes, int n_in,
                              void* d_out, int out_size, void* d_ws, size_t ws_size,
                              hipStream_t stream) {
  (void)in_sizes; (void)n_in; (void)out_size; (void)ws_size;
  const float* x      = (const float*)d_in[0];
  const float* kv0    = (const float*)d_in[1];
  const float* kst0   = (const float*)d_in[2];
  const float* kbuf   = (const float*)d_in[3];
  const float* vbufw  = (const float*)d_in[4];
  const float* Wq_lin = (const float*)d_in[5];
  const float* bq_lin = (const float*)d_in[6];
  const float* Wk_lin = (const float*)d_in[7];
  const float* bk_lin = (const float*)d_in[8];
  const float* Wv_lin = (const float*)d_in[9];
  const float* bv_lin = (const float*)d_in[10];
  const float* Wo_lin = (const float*)d_in[11];
  const float* bo_lin = (const float*)d_in[12];
  const float* Wq     = (const float*)d_in[13];
  const float* bq     = (const float*)d_in[14];
  const float* Wk     = (const float*)d_in[15];
  const float* bk     = (const float*)d_in[16];
  const float* Wv     = (const float*)d_in[17];
  const float* bv     = (const float*)d_in[18];
  const float* Wo     = (const float*)d_in[19];
  const float* bo     = (const float*)d_in[20];
  const float* gamma  = (const float*)d_in[21];
  const float* beta   = (const float*)d_in[22];

  float* out = (float*)d_out;
  float* kv_out  = out + 8388608;
  float* kst_out = out + 8388608 + 1118208;

  float* ws = (float*)d_ws;
  const size_t MF = 1024 * 1024;
  unsigned short* x_bf   = (unsigned short*)(ws);              // [0,4)
  unsigned short* qkv_b  = (unsigned short*)(ws + 4 * MF);     // [4,10)  Q|K|V bf16
  unsigned short* vT     = (unsigned short*)(ws + 10 * MF);    // [10,14)
  unsigned short* KVc_t  = (unsigned short*)(ws + 14 * MF);    // [14,23)
  unsigned short* kstc   = (unsigned short*)(ws + 23 * MF);    // [23,23.2)
  unsigned short* KVp_t  = (unsigned short*)(ws + 24 * MF);    // [24,33)
  unsigned short* kstp   = (unsigned short*)(ws + 33 * MF);    // [33,33.2)
  unsigned short* outs_bf = (unsigned short*)(ws + 34 * MF);   // [34,38)
  unsigned short* tmp_b  = (unsigned short*)(ws + 38 * MF);    // [38,42)
  unsigned short* x1b    = (unsigned short*)(ws + 42 * MF);    // [42,46)
  unsigned short* q2b    = (unsigned short*)(ws + 46 * MF);    // [46,50)
  unsigned short* winb   = (unsigned short*)(ws + 50 * MF);    // [50,54)
  unsigned short* tmp2_b = (unsigned short*)(ws + 54 * MF);    // [54,58)
  float* klast = ws + 58 * MF;                                 // 4096
  float* vlast = klast + 4096;                                 // 4096
  unsigned short* ukb  = (unsigned short*)(ws + 58 * MF + 8192);   // 262144 bf16
  unsigned short* uvTw = ukb + 262144;                              // 262144 bf16
  unsigned short* Wcomb = (unsigned short*)(ws + 59 * MF);     // 1536*1024 bf16
  unsigned short* WtO1  = (unsigned short*)(ws + 60 * MF);     // 1024*1024 bf16
  unsigned short* WtQ2  = (unsigned short*)(ws + 61 * MF);
  unsigned short* WtO2  = (unsigned short*)(ws + 62 * MF);
  float* bqkv = ws + 63 * MF;                                  // 1536 floats

  dim3 blk(256);
  prep_all<<<9376, blk, 0, stream>>>(x, x_bf,
                                     Wq_lin, Wk_lin, Wv_lin, Wo_lin, Wq, Wo,
                                     bq_lin, bk_lin, bv_lin,
                                     Wcomb, WtO1, WtQ2, WtO2, bqkv,
                                     bk, bv, klast, vlast);
  gemm_mfma<<<768, blk, 0, stream>>>(x_bf, Wcomb, bqkv, (float*)0, qkv_b, 8192, QKVN, 1024);
  transV<<<2048, blk, 0, stream>>>(qkv_b, vT);
  phaseA2<<<1024, blk, 0, stream>>>(qkv_b, vT, KVc_t, kstc);
  phaseB3<<<585, blk, 0, stream>>>(KVc_t, kstc, kv0, kst0, KVp_t, kstp, kv_out, kst_out);
  phaseC4<<<1024, blk, 0, stream>>>(qkv_b, vT, KVp_t, kstp, outs_bf);
  gemm_mfma<<<512, blk, 0, stream>>>(outs_bf, WtO1, bo_lin, (float*)0, tmp_b, 8192, 1024, 1024);
  ln_add2<<<8192, blk, 0, stream>>>(x, (const unsigned short*)0, tmp_b, gamma, beta, (float*)0, x1b);
  gemm_mfma<<<512, blk, 0, stream>>>(x1b, WtQ2, bq, (float*)0, q2b, 8192, 1024, 1024);
  lastrow_qkv2<<<512, blk, 0, stream>>>(x1b, Wk, Wv, klast, vlast);
  prep_window<<<64, blk, 0, stream>>>(kbuf, vbufw, klast, vlast, ukb, uvTw);
  window_attn2<<<1024, blk, 0, stream>>>(q2b, ukb, uvTw, winb);
  gemm_mfma<<<512, blk, 0, stream>>>(winb, WtO2, bo, (float*)0, tmp2_b, 8192, 1024, 1024);
  ln_add2<<<8192, blk, 0, stream>>>((const float*)0, x1b, tmp2_b, gamma, beta, out, (unsigned short*)0);
}